// Round 13
// baseline (194.644 us; speedup 1.0000x reference)
//
#include <hip/hip_runtime.h>

typedef __attribute__((ext_vector_type(8))) short short8;
typedef __attribute__((ext_vector_type(4))) float f32x4;
typedef __attribute__((ext_vector_type(4))) unsigned int u32x4;

#define NTOK 4096
#define DIM  256
#define P_STRIDE 72        // P row stride elems (144 B)
#define TILE_ELEMS 32768   // ushorts per 64KB tile image (Ks 16384 | Kt 16384)
#define CNT_OFF (16u * 1024u * 1024u)   // grid-barrier counter after 16 MB of images

__device__ __forceinline__ unsigned pack2bf(float a, float b) {
  unsigned ua = __builtin_bit_cast(unsigned, a) + 0x8000u;
  unsigned ub = __builtin_bit_cast(unsigned, b) + 0x8000u;
  return __builtin_amdgcn_perm(ub, ua, 0x07060302u); // low=bf16(a), high=bf16(b)
}

// PV: O[s][dt] += P(strips of qh, all 64 keys) x V(d-quarter dq)
__device__ __forceinline__ void pv_step(const unsigned short* __restrict__ pr,
                                        const unsigned short* __restrict__ kt,
                                        f32x4 (&o)[2][4],
                                        int qh, int dq, int quad, int ln) {
  #pragma unroll
  for (int ks = 0; ks < 2; ++ks) {
    const int pos = (ks * 4 + quad) ^ ((ln >> 3) << 1);
    short8 ap[2], bv[4];
    #pragma unroll
    for (int s = 0; s < 2; ++s)
      ap[s] = *(const short8*)(&pr[(qh * 32 + s * 16 + ln) * P_STRIDE + (pos << 3)]);
    const unsigned short* kb = kt + (ks * 4 + quad) * 2048 + (dq * 64 + ln) * 8;
    #pragma unroll
    for (int dt = 0; dt < 4; ++dt) bv[dt] = *(const short8*)(kb + dt * 128);
    #pragma unroll
    for (int s = 0; s < 2; ++s)
      #pragma unroll
      for (int dt = 0; dt < 4; ++dt)
        o[s][dt] = __builtin_amdgcn_mfma_f32_16x16x32_bf16(ap[s], bv[dt], o[s][dt], 0, 0, 0);
  }
}

// ---- fused: per-block tile-image prep + grid barrier + R8 flash loop -----
__global__ __launch_bounds__(512, 1)
void fa_kernel(const float* __restrict__ X, unsigned short* __restrict__ Img,
               int* __restrict__ cnt, float* __restrict__ Out) {
  __shared__ __align__(16) unsigned short ksb[2][16384];        // 64 KB
  __shared__ __align__(16) unsigned short ktb[2][16384];        // 64 KB
  __shared__ __align__(16) unsigned short pb[2][64 * P_STRIDE]; // 18 KB
  __shared__ float lbuf[64][4];                                 // 1 KB

  const int tid  = threadIdx.x;
  const int b    = blockIdx.x & 3;
  const int qblk = blockIdx.x >> 2;
  const int wave = tid >> 6;
  const int lane = tid & 63;
  const int ln   = lane & 15;
  const int quad = lane >> 4;
  const int swz  = ln & 7;
  const int qh   = wave & 1;
  const int role = wave >> 1;

  // ============ phase 1: build this block's own tile image ================
  // Img[b][t] = [ Ks: 64 rows x 32 chunks(16B), chunk c at (c ^ (r&7))
  //             | Kt: 8 kb-blocks x 256 d x 8 tokens ]
  {
    const float* src = X + ((size_t)b * NTOK + qblk * 64) * DIM;
    unsigned short* dst = Img + (size_t)(b * 64 + qblk) * TILE_ELEMS;
    // Ks: 2048 16B-chunks, 4 per thread (512 threads)
    #pragma unroll
    for (int i = 0; i < 4; ++i) {
      int c   = i * 512 + tid;
      int r   = c >> 5;
      int cc  = c & 31;
      const float* s = src + r * DIM + cc * 8;
      f32x4 f0 = *(const f32x4*)s;
      f32x4 f1 = *(const f32x4*)(s + 4);
      union { unsigned u[4]; u32x4 v; } p;
      p.u[0] = pack2bf(f0[0], f0[1]);
      p.u[1] = pack2bf(f0[2], f0[3]);
      p.u[2] = pack2bf(f1[0], f1[1]);
      p.u[3] = pack2bf(f1[2], f1[3]);
      *(u32x4*)(dst + r * 256 + ((cc ^ (r & 7)) << 3)) = p.v;
    }
    // Kt: threads 0..255 -> d; each does 8 kb-blocks. threads 256..511 idle here.
    if (tid < 256) {
      const int d = tid;
      #pragma unroll
      for (int kb = 0; kb < 8; ++kb) {
        float f[8];
        #pragma unroll
        for (int i = 0; i < 8; ++i) f[i] = src[(kb * 8 + i) * DIM + d];
        union { unsigned u[4]; u32x4 v; } p;
        p.u[0] = pack2bf(f[0], f[1]);
        p.u[1] = pack2bf(f[2], f[3]);
        p.u[2] = pack2bf(f[4], f[5]);
        p.u[3] = pack2bf(f[6], f[7]);
        *(u32x4*)(dst + 16384 + kb * 2048 + d * 8) = p.v;
      }
    }
  }

  // ============ grid barrier (all 256 blocks co-resident: 1 block/CU) =====
  __syncthreads();
  if (tid == 0) {
    __hip_atomic_fetch_add(cnt, 1, __ATOMIC_RELEASE, __HIP_MEMORY_SCOPE_AGENT);
    while (__hip_atomic_load(cnt, __ATOMIC_ACQUIRE, __HIP_MEMORY_SCOPE_AGENT) < 256)
      __builtin_amdgcn_s_sleep(8);
  }
  __syncthreads();

  // ============ phase 2: R8 flash-attention loop (verbatim) ===============
  const unsigned short* imgb  = Img + (size_t)b * 64 * TILE_ELEMS;
  const char*           imgbc = (const char*)imgb;

  short8 aQ[2][8];
  #pragma unroll
  for (int s = 0; s < 2; ++s) {
    const unsigned short* qrow =
        imgb + (size_t)qblk * TILE_ELEMS + (qh * 32 + s * 16 + ln) * 256;
    #pragma unroll
    for (int ds = 0; ds < 8; ++ds)
      aQ[s][ds] = *(const short8*)(qrow + (((ds * 4 + quad) ^ swz) << 3));
  }

  f32x4 o[2][4];
  #pragma unroll
  for (int s = 0; s < 2; ++s)
    #pragma unroll
    for (int dt = 0; dt < 4; ++dt) o[s][dt] = (f32x4)(0.0f);
  float lrow[2][4] = {{0.f,0.f,0.f,0.f},{0.f,0.f,0.f,0.f}};

  const float c2 = 0.0901684400f;  // log2(e)/sqrt(256)
  const int pwPos = ((role * 2 + (ln >> 3)) ^ ((quad >> 1) << 1)) << 3;
  const int pwCol = ln & 7;

  const bool dmaKs = wave < 4;
  const int  dmaQ  = wave & 3;
  const char* gK = imgbc + (size_t)dmaQ * 8192 + (size_t)lane * 16;

  if (dmaKs) {
    #pragma unroll
    for (int i = 0; i < 8; ++i)
      __builtin_amdgcn_global_load_lds(
          (const __attribute__((address_space(1))) unsigned*)(gK + i * 1024),
          (__attribute__((address_space(3))) unsigned*)(&ksb[0][dmaQ * 4096 + i * 512]),
          16, 0, 0);
  }

  for (int t = 0; t < 64; ++t) {
    __syncthreads();  // drains last iter's DMA; Ks(t)/Kt(t-1)/P(t-1) ready
    const int buf = t & 1;

    if (dmaKs) {
      if (t < 63) {
        const char* g = gK + (size_t)(t + 1) * 65536;
        unsigned short* l = &ksb[buf ^ 1][dmaQ * 4096];
        #pragma unroll
        for (int i = 0; i < 8; ++i)
          __builtin_amdgcn_global_load_lds(
              (const __attribute__((address_space(1))) unsigned*)(g + i * 1024),
              (__attribute__((address_space(3))) unsigned*)(l + i * 512),
              16, 0, 0);
      }
    } else {
      const char* g = gK + (size_t)t * 65536 + 32768;
      unsigned short* l = &ktb[buf][dmaQ * 4096];
      #pragma unroll
      for (int i = 0; i < 8; ++i)
        __builtin_amdgcn_global_load_lds(
            (const __attribute__((address_space(1))) unsigned*)(g + i * 1024),
            (__attribute__((address_space(3))) unsigned*)(l + i * 512),
            16, 0, 0);
    }

    // --- QK(t): keys role*16..+15, both strips ---
    f32x4 sf0 = (f32x4)(0.0f), sf1 = (f32x4)(0.0f);
    {
      const unsigned short* krow = &ksb[buf][(role * 16 + ln) * 256];
      #pragma unroll
      for (int ds = 0; ds < 8; ++ds) {
        short8 bk = *(const short8*)(krow + (((ds * 4 + quad) ^ swz) << 3));
        sf0 = __builtin_amdgcn_mfma_f32_16x16x32_bf16(aQ[0][ds], bk, sf0, 0, 0, 0);
        sf1 = __builtin_amdgcn_mfma_f32_16x16x32_bf16(aQ[1][ds], bk, sf1, 0, 0, 0);
      }
    }
    // --- softmax numerators; packed conflict-managed P store ---
    {
      unsigned short* pw = pb[buf];
      #pragma unroll
      for (int j = 0; j < 4; ++j) {
        float p0 = __builtin_amdgcn_exp2f(sf0[j] * c2);
        float p1 = __builtin_amdgcn_exp2f(sf1[j] * c2);
        lrow[0][j] += p0;
        lrow[1][j] += p1;
        unsigned q0 = __builtin_bit_cast(unsigned, p0);
        unsigned q1 = __builtin_bit_cast(unsigned, p1);
        unsigned n0 = (unsigned)__builtin_amdgcn_mov_dpp((int)q0, 0xB1, 0xF, 0xF, true);
        unsigned n1 = (unsigned)__builtin_amdgcn_mov_dpp((int)q1, 0xB1, 0xF, 0xF, true);
        if ((ln & 1) == 0) {
          const int r0 = qh * 32 + quad * 4 + j;
          unsigned d0 = pack2bf(__builtin_bit_cast(float, q0), __builtin_bit_cast(float, n0));
          unsigned d1 = pack2bf(__builtin_bit_cast(float, q1), __builtin_bit_cast(float, n1));
          *(unsigned*)(&pw[r0 * P_STRIDE + pwPos + pwCol]) = d0;
          *(unsigned*)(&pw[(r0 + 16) * P_STRIDE + pwPos + pwCol]) = d1;
        }
      }
    }

    if (t > 0)
      pv_step(pb[buf ^ 1], ktb[buf ^ 1], o, qh, role, quad, ln);
  }

  __syncthreads();  // P(63), Kt(63) resident
  pv_step(pb[1], ktb[1], o, qh, role, quad, ln);

  // --- merge l across the 4 roles, divide, store ---
  #pragma unroll
  for (int off = 1; off < 16; off <<= 1)
    #pragma unroll
    for (int s = 0; s < 2; ++s)
      #pragma unroll
      for (int j = 0; j < 4; ++j)
        lrow[s][j] += __shfl_xor(lrow[s][j], off, 64);
  if (ln == 0) {
    #pragma unroll
    for (int s = 0; s < 2; ++s)
      #pragma unroll
      for (int j = 0; j < 4; ++j)
        lbuf[qh * 32 + s * 16 + quad * 4 + j][role] = lrow[s][j];
  }
  __syncthreads();

  #pragma unroll
  for (int s = 0; s < 2; ++s) {
    float* outp = Out + (size_t)(b * NTOK + qblk * 64 + qh * 32 + s * 16) * DIM + role * 64;
    #pragma unroll
    for (int j = 0; j < 4; ++j) {
      const int row = s * 16 + quad * 4 + j;
      f32x4 lv = *(const f32x4*)lbuf[qh * 32 + row];
      const float rl = 1.0f / (lv[0] + lv[1] + lv[2] + lv[3]);
      #pragma unroll
      for (int dt = 0; dt < 4; ++dt)
        outp[(size_t)(quad * 4 + j) * DIM + dt * 16 + ln] = o[s][dt][j] * rl;
    }
  }
}

extern "C" void kernel_launch(void* const* d_in, const int* in_sizes, int n_in,
                              void* d_out, int out_size, void* d_ws, size_t ws_size,
                              hipStream_t stream) {
  const float* X = (const float*)d_in[0];       // x: fp32 [4,4096,256]
  float* Out = (float*)d_out;                   // fp32 [4,4096,256]
  unsigned short* Img = (unsigned short*)d_ws;  // 16 MB bf16 tile images
  int* cnt = (int*)((char*)d_ws + CNT_OFF);
  (void)in_sizes; (void)n_in; (void)out_size; (void)ws_size;
  hipMemsetAsync(cnt, 0, 4, stream);            // reset grid-barrier counter
  hipLaunchKernelGGL(fa_kernel, dim3(256), dim3(512), 0, stream, X, Img, cnt, Out);
}